// Round 2
// baseline (3669.656 us; speedup 1.0000x reference)
//
#include <hip/hip_runtime.h>
#include <math.h>

#define BATCH 4
#define CIN   512
#define PABN  64
#define HW    4096

// ---- workspace layout (in floats), total ~23.6M floats = 90 MB ----
#define OFF_XT   ((size_t)0)
#define OFF_XC   (OFF_XT  + (size_t)BATCH*PABN*HW)   //  1,048,576
#define OFF_XBT  (OFF_XC  + (size_t)BATCH*PABN*HW)   //  2,097,152
#define OFF_O    (OFF_XBT + (size_t)BATCH*HW*CIN)    // 10,485,760
#define OFF_WBT  (OFF_O   + (size_t)BATCH*HW*CIN)    // 18,874,368
#define OFF_WOT  (OFF_WBT + (size_t)9*CIN*CIN)       // 21,233,664
#define OFF_Z    (OFF_WOT + (size_t)9*CIN*CIN)       // 23,592,960

__device__ inline unsigned int f2bf(float f) {      // fp32 -> bf16 bits (RNE)
    unsigned int u = __float_as_uint(f);
    return (u + 0x7fffu + ((u >> 16) & 1u)) >> 16;
}

// ---------------------------------------------------------------------------
__global__ __launch_bounds__(64) void k_zero(float* __restrict__ Z) {
    if (threadIdx.x < 4) Z[threadIdx.x] = 0.f;
}

// ---------------------------------------------------------------------------
// Transpose conv weights [O][I][3][3] -> wT[k][o][i]  (k = kh*3+kw)
__global__ __launch_bounds__(256) void k_wT(const float* __restrict__ w,
                                            float* __restrict__ wT)
{
    int o = blockIdx.x;
    int i = blockIdx.y * 256 + threadIdx.x;
    const float* src = w + ((size_t)o * CIN + i) * 9;
    float v[9];
#pragma unroll
    for (int k = 0; k < 9; k++) v[k] = src[k];
#pragma unroll
    for (int k = 0; k < 9; k++)
        wT[((size_t)k * CIN + o) * CIN + i] = v[k];
}

// ---------------------------------------------------------------------------
// 1x1 convs (top & center): out[p][n] = sum_c w[p][c] x[c][n] + bias[p]
// grid: (32 n-tiles, 8)  z = batch*2 + which
__global__ __launch_bounds__(256) void k_gemm_pc(const float* __restrict__ x,
        const float* __restrict__ w_top, const float* __restrict__ b_top,
        const float* __restrict__ w_cen, const float* __restrict__ b_cen,
        float* __restrict__ xt, float* __restrict__ xc)
{
    int z = blockIdx.y;
    int b = z >> 1, which = z & 1;
    const float* w    = which ? w_cen : w_top;
    const float* bias = which ? b_cen : b_top;
    float* out        = which ? xc    : xt;
    int n0 = blockIdx.x * 128;

    __shared__ float a_s[16][68];
    __shared__ float b_s[16][132];
    int t = threadIdx.x;
    int tn = t & 15, tp = t >> 4;
    int n_off = tn * 8, p_off = tp * 4;
    float acc[4][8];
#pragma unroll
    for (int i = 0; i < 4; i++)
#pragma unroll
        for (int j = 0; j < 8; j++) acc[i][j] = 0.f;

    const float* xb = x + (size_t)b * CIN * HW;
    int a_pp = t >> 2, a_cc = (t & 3) * 4;
    int b_cc = t >> 4, b_nn = (t & 15) * 8;

    for (int c0 = 0; c0 < CIN; c0 += 16) {
        {
            float4 v = *(const float4*)(w + (size_t)a_pp * CIN + c0 + a_cc);
            a_s[a_cc + 0][a_pp] = v.x; a_s[a_cc + 1][a_pp] = v.y;
            a_s[a_cc + 2][a_pp] = v.z; a_s[a_cc + 3][a_pp] = v.w;
        }
        {
            const float* src = xb + (size_t)(c0 + b_cc) * HW + n0 + b_nn;
            *(float4*)&b_s[b_cc][b_nn]     = *(const float4*)(src);
            *(float4*)&b_s[b_cc][b_nn + 4] = *(const float4*)(src + 4);
        }
        __syncthreads();
#pragma unroll
        for (int kk = 0; kk < 16; kk++) {
            float ra[4], rb[8];
            *(float4*)ra       = *(const float4*)&a_s[kk][p_off];
            *(float4*)rb       = *(const float4*)&b_s[kk][n_off];
            *(float4*)(rb + 4) = *(const float4*)&b_s[kk][n_off + 4];
#pragma unroll
            for (int i = 0; i < 4; i++)
#pragma unroll
                for (int j = 0; j < 8; j++) acc[i][j] += ra[i] * rb[j];
        }
        __syncthreads();
    }
#pragma unroll
    for (int i = 0; i < 4; i++) {
        float bv = bias[p_off + i];
        float* dst = out + ((size_t)b * PABN + p_off + i) * HW + n0 + n_off;
        *(float4*)dst       = make_float4(acc[i][0] + bv, acc[i][1] + bv,
                                          acc[i][2] + bv, acc[i][3] + bv);
        *(float4*)(dst + 4) = make_float4(acc[i][4] + bv, acc[i][5] + bv,
                                          acc[i][6] + bv, acc[i][7] + bv);
    }
}

// ---------------------------------------------------------------------------
// conv3x3 as 9 shifted GEMMs.  in: [C][HW] (per batch), wT: [k][o][i],
// out: NMAJOR ? out[b][n][o] : out[b][o][n].
// FUSED: B-operand becomes in + add*invZ (elementwise, same layout).
// grid: (32 n-tiles, 4 o-tiles, B)
template <bool NMAJOR, bool FUSED>
__global__ __launch_bounds__(256) void k_conv3(const float* __restrict__ in,
        const float* __restrict__ add, const float* __restrict__ Zp,
        const float* __restrict__ wT, const float* __restrict__ bias,
        float* __restrict__ out)
{
    int n0 = blockIdx.x * 128;
    int o0 = blockIdx.y * 128;
    int b  = blockIdx.z;

    float invZ = 0.f;
    if constexpr (FUSED) invZ = 1.0f / Zp[b];

    __shared__ float a_s[32][132];
    __shared__ float b_s[32][132];
    int t = threadIdx.x;
    int to = t >> 4, tn = t & 15;
    int o_off = to * 8, n_off = tn * 8;
    float acc[8][8];
#pragma unroll
    for (int i = 0; i < 8; i++)
#pragma unroll
        for (int j = 0; j < 8; j++) acc[i][j] = 0.f;

    const float* inb  = in + (size_t)b * CIN * HW;
    const float* addb = FUSED ? (add + (size_t)b * CIN * HW) : nullptr;
    int a_oo = t >> 1, a_ii = (t & 1) * 16;
    int b_ii = t >> 3, b_nn = (t & 7) * 16;

    for (int k9 = 0; k9 < 9; k9++) {
        int kh = k9 / 3 - 1, kw = k9 % 3 - 1;
        const float* wk = wT + (size_t)k9 * CIN * CIN;
        int shift = kh * 64 + kw;
        for (int i0 = 0; i0 < CIN; i0 += 32) {
            { // A tile: a_s[ii][oo] from wT[k][o][i]
                const float* src = wk + (size_t)(o0 + a_oo) * CIN + i0 + a_ii;
#pragma unroll
                for (int j = 0; j < 16; j += 4) {
                    float4 v = *(const float4*)(src + j);
                    a_s[a_ii + j + 0][a_oo] = v.x;
                    a_s[a_ii + j + 1][a_oo] = v.y;
                    a_s[a_ii + j + 2][a_oo] = v.z;
                    a_s[a_ii + j + 3][a_oo] = v.w;
                }
            }
            { // B tile: shifted, masked (x + O*invZ)
                size_t rowoff = (size_t)(i0 + b_ii) * HW;
                const float* src = inb + rowoff;
                int nbase = n0 + b_nn;
                int hh = (nbase >> 6) + kh;
                int wbase = (nbase & 63);
                bool hok = (unsigned)hh < 64u;
                if (hok && (wbase + kw) >= 0 && (wbase + 15 + kw) < 64) {
                    const float* s2 = src + nbase + shift;
#pragma unroll
                    for (int j = 0; j < 16; j += 4) {
                        float4 v = *(const float4*)(s2 + j);
                        if constexpr (FUSED) {
                            float4 w4 = *(const float4*)(addb + rowoff + nbase + shift + j);
                            v.x += w4.x * invZ; v.y += w4.y * invZ;
                            v.z += w4.z * invZ; v.w += w4.w * invZ;
                        }
                        *(float4*)&b_s[b_ii][b_nn + j] = v;
                    }
                } else {
#pragma unroll
                    for (int j = 0; j < 16; j++) {
                        int ww = wbase + j + kw;
                        bool ok = hok && ((unsigned)ww < 64u);
                        float vv = 0.f;
                        if (ok) {
                            vv = src[nbase + j + shift];
                            if constexpr (FUSED)
                                vv += addb[rowoff + nbase + j + shift] * invZ;
                        }
                        b_s[b_ii][b_nn + j] = vv;
                    }
                }
            }
            __syncthreads();
#pragma unroll
            for (int kk = 0; kk < 32; kk++) {
                float ra[8], rb[8];
                *(float4*)ra       = *(const float4*)&a_s[kk][o_off];
                *(float4*)(ra + 4) = *(const float4*)&a_s[kk][o_off + 4];
                *(float4*)rb       = *(const float4*)&b_s[kk][n_off];
                *(float4*)(rb + 4) = *(const float4*)&b_s[kk][n_off + 4];
#pragma unroll
                for (int i = 0; i < 8; i++)
#pragma unroll
                    for (int j = 0; j < 8; j++) acc[i][j] += ra[i] * rb[j];
            }
            __syncthreads();
        }
    }
    float bv[8];
#pragma unroll
    for (int i = 0; i < 8; i++) bv[i] = bias[o0 + o_off + i];
    if (NMAJOR) {
#pragma unroll
        for (int j = 0; j < 8; j++) {
            float* dst = out + ((size_t)b * HW + n0 + n_off + j) * CIN + o0 + o_off;
            *(float4*)dst       = make_float4(acc[0][j] + bv[0], acc[1][j] + bv[1],
                                              acc[2][j] + bv[2], acc[3][j] + bv[3]);
            *(float4*)(dst + 4) = make_float4(acc[4][j] + bv[4], acc[5][j] + bv[5],
                                              acc[6][j] + bv[6], acc[7][j] + bv[7]);
        }
    } else {
#pragma unroll
        for (int i = 0; i < 8; i++) {
            float* dst = out + ((size_t)b * CIN + o0 + o_off + i) * HW + n0 + n_off;
            *(float4*)dst       = make_float4(acc[i][0] + bv[i], acc[i][1] + bv[i],
                                              acc[i][2] + bv[i], acc[i][3] + bv[i]);
            *(float4*)(dst + 4) = make_float4(acc[i][4] + bv[i], acc[i][5] + bv[i],
                                              acc[i][6] + bv[i], acc[i][7] + bv[i]);
        }
    }
}

// ---------------------------------------------------------------------------
// Fused attention: for an n-tile of 32 rows, loop m-tiles of 32:
//   S[n][m] = sum_p xc[p][n]*xt[p][m];  P = exp(S);  Z += sum(P);
//   O[n][c] += P[n][m] * xbT[m][c]   (O left UNSCALED; 1/Z applied later)
// grid: (HW/32, B), 256 threads.
__global__ __launch_bounds__(256) void k_attn_fused(
        const float* __restrict__ xc, const float* __restrict__ xt,
        const float* __restrict__ xbT, float* __restrict__ O,
        float* __restrict__ Z)
{
    int nn0 = blockIdx.x * 32;
    int b   = blockIdx.y;

    __shared__ float xc_s[64][36];
    __shared__ float xt_s[64][36];
    __shared__ float p_s[32][36];
    __shared__ __align__(16) unsigned short xb_s[32][520];
    __shared__ float red[256];

    int t = threadIdx.x;
    const float* xcb = xc  + (size_t)b * PABN * HW;
    const float* xtb = xt  + (size_t)b * PABN * HW;
    const float* xbb = xbT + (size_t)b * HW * CIN;

    { // stage xc tile [64p][32n] once
        int p = t >> 2, q = (t & 3) * 8;
        const float* src = xcb + (size_t)p * HW + nn0 + q;
        *(float4*)&xc_s[p][q]     = *(const float4*)src;
        *(float4*)&xc_s[p][q + 4] = *(const float4*)(src + 4);
    }

    float acc[4][16];
#pragma unroll
    for (int i = 0; i < 4; i++)
#pragma unroll
        for (int j = 0; j < 16; j++) acc[i][j] = 0.f;
    float zacc = 0.f;

    int tn2 = t & 15, tm2 = t >> 4;          // S thread tile: 2n x 2m
    int n_g = t >> 5, c_g = t & 31;          // PV thread tile: 4n x 16c

    for (int m0 = 0; m0 < HW; m0 += 32) {
        __syncthreads();                     // prev iter's reads done
        { // stage xt tile [64p][32m]
            int p = t >> 2, q = (t & 3) * 8;
            const float* src = xtb + (size_t)p * HW + m0 + q;
            *(float4*)&xt_s[p][q]     = *(const float4*)src;
            *(float4*)&xt_s[p][q + 4] = *(const float4*)(src + 4);
        }
        { // stage xb tile [32m][512c] as bf16
#pragma unroll 4
            for (int k = 0; k < 16; k++) {
                int idx = t + k * 256;       // float4 index in [0,4096)
                int row = idx >> 7, c4 = idx & 127;
                float4 v = *(const float4*)(xbb + (size_t)(m0 + row) * CIN + c4 * 4);
                uint2 pk;
                pk.x = f2bf(v.x) | (f2bf(v.y) << 16);
                pk.y = f2bf(v.z) | (f2bf(v.w) << 16);
                *(uint2*)&xb_s[row][c4 * 4] = pk;
            }
        }
        __syncthreads();                     // stages visible

        // ---- S tile (K=64) ----
        float s00 = 0.f, s01 = 0.f, s10 = 0.f, s11 = 0.f;
#pragma unroll 16
        for (int p = 0; p < 64; p++) {
            float2 a = *(const float2*)&xc_s[p][tn2 * 2];
            float2 c = *(const float2*)&xt_s[p][tm2 * 2];
            s00 += a.x * c.x; s01 += a.x * c.y;
            s10 += a.y * c.x; s11 += a.y * c.y;
        }
        float e00 = __expf(s00), e01 = __expf(s01);
        float e10 = __expf(s10), e11 = __expf(s11);
        zacc += (e00 + e01) + (e10 + e11);
        p_s[tm2 * 2    ][tn2 * 2    ] = e00;
        p_s[tm2 * 2 + 1][tn2 * 2    ] = e01;
        p_s[tm2 * 2    ][tn2 * 2 + 1] = e10;
        p_s[tm2 * 2 + 1][tn2 * 2 + 1] = e11;
        __syncthreads();                     // p_s visible

        // ---- PV: O[32n][512c] += P[32][32] * xb[32][512] ----
#pragma unroll 4
        for (int kk = 0; kk < 32; kk++) {
            float4 pa = *(const float4*)&p_s[kk][n_g * 4];
            uint4 b0 = *(const uint4*)&xb_s[kk][c_g * 8];
            uint4 b1 = *(const uint4*)&xb_s[kk][256 + c_g * 8];
            float f0[8], f1[8];
            f0[0] = __uint_as_float(b0.x << 16); f0[1] = __uint_as_float(b0.x & 0xffff0000u);
            f0[2] = __uint_as_float(b0.y << 16); f0[3] = __uint_as_float(b0.y & 0xffff0000u);
            f0[4] = __uint_as_float(b0.z << 16); f0[5] = __uint_as_float(b0.z & 0xffff0000u);
            f0[6] = __uint_as_float(b0.w << 16); f0[7] = __uint_as_float(b0.w & 0xffff0000u);
            f1[0] = __uint_as_float(b1.x << 16); f1[1] = __uint_as_float(b1.x & 0xffff0000u);
            f1[2] = __uint_as_float(b1.y << 16); f1[3] = __uint_as_float(b1.y & 0xffff0000u);
            f1[4] = __uint_as_float(b1.z << 16); f1[5] = __uint_as_float(b1.z & 0xffff0000u);
            f1[6] = __uint_as_float(b1.w << 16); f1[7] = __uint_as_float(b1.w & 0xffff0000u);
            float pv[4] = { pa.x, pa.y, pa.z, pa.w };
#pragma unroll
            for (int i = 0; i < 4; i++) {
#pragma unroll
                for (int j = 0; j < 8; j++) acc[i][j]     += pv[i] * f0[j];
#pragma unroll
                for (int j = 0; j < 8; j++) acc[i][j + 8] += pv[i] * f1[j];
            }
        }
    }

    // ---- Z block reduction ----
    red[t] = zacc;
    __syncthreads();
    for (int s = 128; s > 0; s >>= 1) {
        if (t < s) red[t] += red[t + s];
        __syncthreads();
    }
    if (t == 0) atomicAdd(Z + b, red[0]);

    // ---- O write (unscaled). thread covers n = nn0+n_g*4+i,
    //      c = {c_g*8..+7} u {256+c_g*8..+7}
#pragma unroll
    for (int i = 0; i < 4; i++) {
        float* dst = O + ((size_t)b * HW + nn0 + n_g * 4 + i) * CIN;
        *(float4*)(dst + c_g * 8)           = make_float4(acc[i][0], acc[i][1], acc[i][2], acc[i][3]);
        *(float4*)(dst + c_g * 8 + 4)       = make_float4(acc[i][4], acc[i][5], acc[i][6], acc[i][7]);
        *(float4*)(dst + 256 + c_g * 8)     = make_float4(acc[i][8], acc[i][9], acc[i][10], acc[i][11]);
        *(float4*)(dst + 256 + c_g * 8 + 4) = make_float4(acc[i][12], acc[i][13], acc[i][14], acc[i][15]);
    }
}

// ---------------------------------------------------------------------------
extern "C" void kernel_launch(void* const* d_in, const int* in_sizes, int n_in,
                              void* d_out, int out_size, void* d_ws, size_t ws_size,
                              hipStream_t stream)
{
    const float* x      = (const float*)d_in[0];
    const float* w_top  = (const float*)d_in[1];
    const float* b_top  = (const float*)d_in[2];
    const float* w_cen  = (const float*)d_in[3];
    const float* b_cen  = (const float*)d_in[4];
    const float* w_bot  = (const float*)d_in[5];
    const float* b_bot  = (const float*)d_in[6];
    const float* w_out  = (const float*)d_in[7];
    const float* b_out  = (const float*)d_in[8];

    float* ws  = (float*)d_ws;
    float* xt  = ws + OFF_XT;
    float* xc  = ws + OFF_XC;
    float* xbT = ws + OFF_XBT;
    float* O   = ws + OFF_O;
    float* wbT = ws + OFF_WBT;
    float* woT = ws + OFF_WOT;
    float* Z   = ws + OFF_Z;

    k_zero<<<1, 64, 0, stream>>>(Z);
    k_wT<<<dim3(CIN, 2), 256, 0, stream>>>(w_bot, wbT);
    k_wT<<<dim3(CIN, 2), 256, 0, stream>>>(w_out, woT);
    k_gemm_pc<<<dim3(32, 8), 256, 0, stream>>>(x, w_top, b_top, w_cen, b_cen, xt, xc);
    k_conv3<true, false><<<dim3(32, 4, BATCH), 256, 0, stream>>>(
        x, nullptr, nullptr, wbT, b_bot, xbT);
    k_attn_fused<<<dim3(HW / 32, BATCH), 256, 0, stream>>>(xc, xt, xbT, O, Z);
    k_conv3<false, true><<<dim3(32, 4, BATCH), 256, 0, stream>>>(
        x, O, Z, woT, b_out, (float*)d_out);
}

// Round 3
// 767.003 us; speedup vs baseline: 4.7844x; 4.7844x over previous
//
#include <hip/hip_runtime.h>
#include <math.h>

#define BATCH 4
#define CIN   512
#define PABN  64
#define HW    4096
#define PROW  4356            // 66*66 padded pixel rows

typedef __attribute__((ext_vector_type(8))) short bfrag;   // 8 bf16
typedef __attribute__((ext_vector_type(4))) float ffrag;   // 4 fp32
#define MFMA(a, b, c) __builtin_amdgcn_mfma_f32_16x16x32_bf16(a, b, c, 0, 0, 0)

__device__ __forceinline__ void gload16(const void* g, void* l) {
    __builtin_amdgcn_global_load_lds(
        (const __attribute__((address_space(1))) unsigned int*)g,
        (__attribute__((address_space(3))) unsigned int*)l, 16, 0, 0);
}

__device__ __forceinline__ unsigned f2bf(float f) {   // fp32 -> bf16 bits, RNE
    unsigned u = __float_as_uint(f);
    return (u + 0x7fffu + ((u >> 16) & 1u)) >> 16;
}

// padded row index for pixel n: (h+1)*66 + (w+1) = n + 2*(n>>6) + 67
__device__ __forceinline__ int prow(int n) { return n + 2 * (n >> 6) + 67; }

// ---------------------------------------------------------------------------
__global__ __launch_bounds__(64) void k_zero(float* __restrict__ Z) {
    if (threadIdx.x < 16) Z[threadIdx.x] = 0.f;
}

__global__ __launch_bounds__(256) void k_fill0(uint4* __restrict__ p) {
    uint4 z; z.x = z.y = z.z = z.w = 0u;
    p[(size_t)blockIdx.x * 256 + threadIdx.x] = z;
}

// w_top/w_cen [64][512] fp32 -> bf16 (layout kept: [p][i], K=i contiguous)
__global__ __launch_bounds__(256) void k_wpc(const float* __restrict__ wt,
        const float* __restrict__ wc, short* __restrict__ ot, short* __restrict__ oc) {
    const float* src = blockIdx.y ? wc : wt;
    short* dst       = blockIdx.y ? oc : ot;
    int idx = (blockIdx.x * 256 + threadIdx.x) * 4;
    float4 v = *(const float4*)(src + idx);
    uint2 u;
    u.x = f2bf(v.x) | (f2bf(v.y) << 16);
    u.y = f2bf(v.z) | (f2bf(v.w) << 16);
    *(uint2*)(dst + idx) = u;
}

// w [O][I][3][3] fp32 -> wT[k][o][i] bf16
__global__ __launch_bounds__(256) void k_w9(const float* __restrict__ wb,
        const float* __restrict__ wo, short* __restrict__ wbT, short* __restrict__ woT) {
    const float* w = blockIdx.z ? wo : wb;
    short* wT      = blockIdx.z ? woT : wbT;
    int o = blockIdx.x;
    int i = blockIdx.y * 256 + threadIdx.x;
    const float* src = w + ((size_t)o * CIN + i) * 9;
    float v[9];
#pragma unroll
    for (int k = 0; k < 9; k++) v[k] = src[k];
#pragma unroll
    for (int k = 0; k < 9; k++)
        wT[((size_t)k * CIN + o) * CIN + i] = (short)f2bf(v[k]);
}

// ---------------------------------------------------------------------------
// x [B][512][4096] fp32 (-> optionally + O channel-major fp32) -> pixel-major
// padded bf16 xp [B][4356][512]. Interior rows only (borders pre-zeroed).
// grid (64 pix-tiles, 8 ch-tiles, B)
template <bool ADD>
__global__ __launch_bounds__(256) void k_padT(const float* __restrict__ x,
        const float* __restrict__ Oc, short* __restrict__ xp) {
    __shared__ float Ts[64][68];
    int t = threadIdx.x;
    int n0 = blockIdx.x * 64, c0 = blockIdx.y * 64, b = blockIdx.z;
    const float* xb = x + ((size_t)b * CIN + c0) * HW;
    const float* ob = ADD ? (Oc + ((size_t)b * CIN + c0) * HW) : nullptr;
#pragma unroll
    for (int j = 0; j < 4; j++) {
        int slot = j * 256 + t;
        int r = slot >> 4, col = (slot & 15) * 4;
        float4 v = *(const float4*)(xb + (size_t)r * HW + n0 + col);
        if (ADD) {
            float4 o4 = *(const float4*)(ob + (size_t)r * HW + n0 + col);
            v.x += o4.x; v.y += o4.y; v.z += o4.z; v.w += o4.w;
        }
        *(float4*)&Ts[r][col] = v;
    }
    __syncthreads();
    short* xpb = xp + (size_t)b * PROW * CIN;
#pragma unroll
    for (int j = 0; j < 2; j++) {
        int slot = j * 256 + t;
        int pix = slot >> 3, ch = (slot & 7) * 8;
        int rp = prow(n0 + pix);
        unsigned pk[4];
#pragma unroll
        for (int k = 0; k < 4; k++)
            pk[k] = f2bf(Ts[ch + 2 * k][pix]) | (f2bf(Ts[ch + 2 * k + 1][pix]) << 16);
        *(uint4*)(xpb + (size_t)rp * CIN + c0 + ch) = *(uint4*)pk;
    }
}

// ---------------------------------------------------------------------------
// 1x1 convs: xt/xc[n][p] = sum_i xp[n][i]*w[p][i] + bias.  M=p(64), N=n(64), K=512
// grid (64 n-tiles, 8: b*2+which)
__global__ __launch_bounds__(256) void k_qk(const short* __restrict__ xp,
        const short* __restrict__ wtop, const short* __restrict__ wcen,
        const float* __restrict__ btop, const float* __restrict__ bcen,
        short* __restrict__ xt, short* __restrict__ xc) {
    __shared__ __align__(16) short As[2048];   // w: 64 rows(p) x 32(i)
    __shared__ __align__(16) short Bs[2048];   // x: 64 rows(n) x 32(i)
    int t = threadIdx.x;
    int n0 = blockIdx.x * 64;
    int b = blockIdx.y >> 1, which = blockIdx.y & 1;
    const short* w    = which ? wcen : wtop;
    const float* bias = which ? bcen : btop;
    short* out        = (which ? xc : xt) + (size_t)b * HW * PABN;
    const short* xb   = xp + (size_t)b * PROW * CIN;

    int arow = t >> 2, ach = t & 3;
    int rp = prow(n0 + arow);
    int lane = t & 63, wid = t >> 6, l15 = lane & 15, q = lane >> 4;
    int wm = wid >> 1, wn = wid & 1;
    ffrag acc[2][2] = {};

    for (int i0 = 0; i0 < CIN; i0 += 32) {
        gload16(w  + (size_t)arow * CIN + i0 + ach * 8, As + t * 8);
        gload16(xb + (size_t)rp   * CIN + i0 + ach * 8, Bs + t * 8);
        __syncthreads();
        bfrag a[2], bb[2];
        a[0]  = *(const bfrag*)(As + (wm * 32 + l15) * 32 + q * 8);
        a[1]  = *(const bfrag*)(As + (wm * 32 + 16 + l15) * 32 + q * 8);
        bb[0] = *(const bfrag*)(Bs + (wn * 32 + l15) * 32 + q * 8);
        bb[1] = *(const bfrag*)(Bs + (wn * 32 + 16 + l15) * 32 + q * 8);
        acc[0][0] = MFMA(a[0], bb[0], acc[0][0]);
        acc[0][1] = MFMA(a[0], bb[1], acc[0][1]);
        acc[1][0] = MFMA(a[1], bb[0], acc[1][0]);
        acc[1][1] = MFMA(a[1], bb[1], acc[1][1]);
        __syncthreads();
    }
#pragma unroll
    for (int mi = 0; mi < 2; mi++) {
        int p = wm * 32 + mi * 16 + q * 4;
        float4 bv = *(const float4*)(bias + p);
#pragma unroll
        for (int ni = 0; ni < 2; ni++) {
            int nn = n0 + wn * 32 + ni * 16 + l15;
            ffrag v = acc[mi][ni];
            uint2 u;
            u.x = f2bf(v.x + bv.x) | (f2bf(v.y + bv.y) << 16);
            u.y = f2bf(v.z + bv.z) | (f2bf(v.w + bv.w) << 16);
            *(uint2*)(out + (size_t)nn * PABN + p) = u;
        }
    }
}

// ---------------------------------------------------------------------------
// conv3x3: out = conv(in, wT) + bias.  M=n(128), N=o(128), K=i over 9 taps.
// FP32OUT: fp32 o-major (d_out). else bf16 o-major (xb channel-major).
// grid (32 n-tiles, 4 o-tiles, B)
template <bool FP32OUT>
__global__ __launch_bounds__(256) void k_conv(const short* __restrict__ xin,
        const short* __restrict__ wT, const float* __restrict__ bias,
        void* __restrict__ outv) {
    __shared__ __align__(16) short As[4096];   // pixels: 128 x 32
    __shared__ __align__(16) short Bs[4096];   // weights: 128(o) x 32
    int t = threadIdx.x;
    int n0 = blockIdx.x * 128, o0 = blockIdx.y * 128, b = blockIdx.z;
    const short* xb = xin + (size_t)b * PROW * CIN;
    int lane = t & 63, wid = t >> 6, l15 = lane & 15, q = lane >> 4;
    int wm = wid >> 1, wn = wid & 1;
    int arow = t >> 2, ach = t & 3;
    int rb1 = prow(n0 + arow), rb2 = prow(n0 + arow + 64);
    ffrag acc[4][4] = {};

    for (int k9 = 0; k9 < 9; k9++) {
        int kh = k9 / 3, kw = k9 - kh * 3;
        int sh = (kh - 1) * 66 + (kw - 1);
        const short* wk = wT + (size_t)k9 * CIN * CIN;
        int r1 = rb1 + sh, r2 = rb2 + sh;
        for (int i0 = 0; i0 < CIN; i0 += 32) {
            gload16(xb + (size_t)r1 * CIN + i0 + ach * 8, As + t * 8);
            gload16(xb + (size_t)r2 * CIN + i0 + ach * 8, As + 2048 + t * 8);
            gload16(wk + (size_t)(o0 + arow) * CIN + i0 + ach * 8, Bs + t * 8);
            gload16(wk + (size_t)(o0 + 64 + arow) * CIN + i0 + ach * 8, Bs + 2048 + t * 8);
            __syncthreads();
            bfrag a[4], bb[4];
#pragma unroll
            for (int mi = 0; mi < 4; mi++)
                a[mi] = *(const bfrag*)(As + (wm * 64 + mi * 16 + l15) * 32 + q * 8);
#pragma unroll
            for (int ni = 0; ni < 4; ni++)
                bb[ni] = *(const bfrag*)(Bs + (wn * 64 + ni * 16 + l15) * 32 + q * 8);
#pragma unroll
            for (int mi = 0; mi < 4; mi++)
#pragma unroll
                for (int ni = 0; ni < 4; ni++)
                    acc[mi][ni] = MFMA(a[mi], bb[ni], acc[mi][ni]);
            __syncthreads();
        }
    }
#pragma unroll
    for (int ni = 0; ni < 4; ni++) {
        int o = o0 + wn * 64 + ni * 16 + l15;
        float bv = bias[o];
#pragma unroll
        for (int mi = 0; mi < 4; mi++) {
            int n = n0 + wm * 64 + mi * 16 + q * 4;
            ffrag v = acc[mi][ni];
            if (FP32OUT) {
                float* out = (float*)outv + (size_t)b * CIN * HW;
                *(float4*)(out + (size_t)o * HW + n) =
                    make_float4(v.x + bv, v.y + bv, v.z + bv, v.w + bv);
            } else {
                short* out = (short*)outv + (size_t)b * CIN * HW;
                uint2 u;
                u.x = f2bf(v.x + bv) | (f2bf(v.y + bv) << 16);
                u.y = f2bf(v.z + bv) | (f2bf(v.w + bv) << 16);
                *(uint2*)(out + (size_t)o * HW + n) = u;
            }
        }
    }
}

// ---------------------------------------------------------------------------
// S-pass (per batch): P[n][m] = exp(sum_p xc[n][p]*xt[m][p]); Z[b] += sum P.
// M=n(128), N=m(128), K=64. grid (32 m-tiles, 32 n-tiles)
__global__ __launch_bounds__(256) void k_S(const short* __restrict__ xc,
        const short* __restrict__ xt, short* __restrict__ P,
        float* __restrict__ Z, int b) {
    __shared__ __align__(16) short SM[16384];  // As [128][64] | Bs [128][64]; reused as T
    short* As = SM;
    short* Bs = SM + 8192;
    int t = threadIdx.x;
    int m0 = blockIdx.x * 128, n0 = blockIdx.y * 128;
    const short* xcb = xc + (size_t)b * HW * PABN;
    const short* xtb = xt + (size_t)b * HW * PABN;
#pragma unroll
    for (int j = 0; j < 4; j++) {
        int slot = j * 256 + t, row = slot >> 3, ch = slot & 7;
        gload16(xcb + (size_t)(n0 + row) * PABN + ch * 8, As + slot * 8);
        gload16(xtb + (size_t)(m0 + row) * PABN + ch * 8, Bs + slot * 8);
    }
    __syncthreads();
    int lane = t & 63, wid = t >> 6, l15 = lane & 15, q = lane >> 4;
    int wm = wid >> 1, wn = wid & 1;
    ffrag acc[4][4] = {};
#pragma unroll
    for (int kc = 0; kc < 2; kc++) {
        bfrag a[4], bb[4];
#pragma unroll
        for (int mi = 0; mi < 4; mi++)
            a[mi] = *(const bfrag*)(As + (wm * 64 + mi * 16 + l15) * 64 + kc * 32 + q * 8);
#pragma unroll
        for (int ni = 0; ni < 4; ni++)
            bb[ni] = *(const bfrag*)(Bs + (wn * 64 + ni * 16 + l15) * 64 + kc * 32 + q * 8);
#pragma unroll
        for (int mi = 0; mi < 4; mi++)
#pragma unroll
            for (int ni = 0; ni < 4; ni++)
                acc[mi][ni] = MFMA(a[mi], bb[ni], acc[mi][ni]);
    }
    __syncthreads();                    // tiles dead; reuse SM as transpose buf
    short* T = SM + wid * 4096;         // per-wave 64x64 bf16
    float zacc = 0.f;
#pragma unroll
    for (int mi = 0; mi < 4; mi++)
#pragma unroll
        for (int ni = 0; ni < 4; ni++) {
            ffrag v = acc[mi][ni];
#pragma unroll
            for (int r = 0; r < 4; r++) {
                float e = __expf(v[r]);
                zacc += e;
                T[(mi * 16 + q * 4 + r) * 64 + ni * 16 + l15] = (short)f2bf(e);
            }
        }
    __syncthreads();
#pragma unroll
    for (int p = 0; p < 8; p++) {
        int r64 = p * 8 + (lane >> 3), c64 = (lane & 7) * 8;
        uint4 v = *(const uint4*)(T + r64 * 64 + c64);
        *(uint4*)(P + (size_t)(n0 + wm * 64 + r64) * HW + m0 + wn * 64 + c64) = v;
    }
#pragma unroll
    for (int off = 32; off > 0; off >>= 1) zacc += __shfl_down(zacc, off, 64);
    if (lane == 0) atomicAdd(Z + b, zacc);
}

// ---------------------------------------------------------------------------
// PV (per batch): O[n][c] = invZ * sum_m xb[c][m]*P[n][m].
// M=c(32), N=n(128), K=4096. grid (32 n-tiles, 16 c-tiles)
__global__ __launch_bounds__(256) void k_PV(const short* __restrict__ xb,
        const short* __restrict__ P, const float* __restrict__ Z,
        float* __restrict__ O, int b) {
    __shared__ __align__(16) short As[1024];   // xb: 32(c) x 32(m)
    __shared__ __align__(16) short Bs[4096];   // P : 128(n) x 32(m)
    int t = threadIdx.x;
    int n0 = blockIdx.x * 128, c0 = blockIdx.y * 32;
    const short* xbb = xb + (size_t)b * CIN * HW;
    int lane = t & 63, wid = t >> 6, l15 = lane & 15, q = lane >> 4;
    int arow = t >> 2, ach = t & 3;
    ffrag acc[2][2] = {};
    for (int m0 = 0; m0 < HW; m0 += 32) {
        if (t < 128)
            gload16(xbb + (size_t)(c0 + arow) * HW + m0 + ach * 8, As + t * 8);
#pragma unroll
        for (int j = 0; j < 2; j++) {
            int slot = j * 256 + t, row = slot >> 2, ch = slot & 3;
            gload16(P + (size_t)(n0 + row) * HW + m0 + ch * 8, Bs + slot * 8);
        }
        __syncthreads();
        bfrag a[2], bb[2];
        a[0]  = *(const bfrag*)(As + l15 * 32 + q * 8);
        a[1]  = *(const bfrag*)(As + (16 + l15) * 32 + q * 8);
        bb[0] = *(const bfrag*)(Bs + (wid * 32 + l15) * 32 + q * 8);
        bb[1] = *(const bfrag*)(Bs + (wid * 32 + 16 + l15) * 32 + q * 8);
        acc[0][0] = MFMA(a[0], bb[0], acc[0][0]);
        acc[0][1] = MFMA(a[0], bb[1], acc[0][1]);
        acc[1][0] = MFMA(a[1], bb[0], acc[1][0]);
        acc[1][1] = MFMA(a[1], bb[1], acc[1][1]);
        __syncthreads();
    }
    float invZ = 1.0f / Z[b];
    float* Ob = O + (size_t)b * HW * CIN;
#pragma unroll
    for (int mi = 0; mi < 2; mi++)
#pragma unroll
        for (int ni = 0; ni < 2; ni++) {
            int c = c0 + mi * 16 + q * 4;
            int n = n0 + wid * 32 + ni * 16 + l15;
            ffrag v = acc[mi][ni];
            *(float4*)(Ob + (size_t)n * CIN + c) =
                make_float4(v.x * invZ, v.y * invZ, v.z * invZ, v.w * invZ);
        }
}

// ---------------------------------------------------------------------------
extern "C" void kernel_launch(void* const* d_in, const int* in_sizes, int n_in,
                              void* d_out, int out_size, void* d_ws, size_t ws_size,
                              hipStream_t stream) {
    const float* x     = (const float*)d_in[0];
    const float* w_top = (const float*)d_in[1];
    const float* b_top = (const float*)d_in[2];
    const float* w_cen = (const float*)d_in[3];
    const float* b_cen = (const float*)d_in[4];
    const float* w_bot = (const float*)d_in[5];
    const float* b_bot = (const float*)d_in[6];
    const float* w_out = (const float*)d_in[7];
    const float* b_out = (const float*)d_in[8];

    char* W = (char*)d_ws;
    short* xp  = (short*)(W);               // 17,842,176 B (also reused as yp)
    short* xt  = (short*)(W + 17842176);    //  2,097,152
    short* xc  = (short*)(W + 19939328);    //  2,097,152
    short* wtb = (short*)(W + 22036480);    //     65,536
    short* wcb = (short*)(W + 22102016);    //     65,536
    short* wbT = (short*)(W + 22167552);    //  4,718,592
    short* woT = (short*)(W + 26886144);    //  4,718,592
    short* xbc = (short*)(W + 31604736);    // 16,777,216
    float* O   = (float*)(W + 48381952);    // 33,554,432
    short* P   = (short*)(W + 81936384);    // 33,554,432 (per-batch)
    float* Z   = (float*)(W + 115490816);   //         64   total ~110.1 MB

    k_zero<<<1, 64, 0, stream>>>(Z);
    k_fill0<<<4356, 256, 0, stream>>>((uint4*)xp);           // zero padded buffer
    k_wpc<<<dim3(32, 2), 256, 0, stream>>>(w_top, w_cen, wtb, wcb);
    k_w9<<<dim3(512, 2, 2), 256, 0, stream>>>(w_bot, w_out, wbT, woT);
    k_padT<false><<<dim3(64, 8, BATCH), 256, 0, stream>>>(x, nullptr, xp);
    k_qk<<<dim3(64, 8), 256, 0, stream>>>(xp, wtb, wcb, b_top, b_cen, xt, xc);
    k_conv<false><<<dim3(32, 4, BATCH), 256, 0, stream>>>(xp, wbT, b_bot, xbc);
    for (int b = 0; b < BATCH; b++) {
        k_S<<<dim3(32, 32), 256, 0, stream>>>(xc, xt, P, Z, b);
        k_PV<<<dim3(32, 16), 256, 0, stream>>>(xbc, P, Z, O, b);
    }
    k_padT<true><<<dim3(64, 8, BATCH), 256, 0, stream>>>(x, O, xp);  // y -> xp (yp)
    k_conv<true><<<dim3(32, 4, BATCH), 256, 0, stream>>>(xp, woT, b_out, (float*)d_out);
}

// Round 4
// 585.050 us; speedup vs baseline: 6.2724x; 1.3110x over previous
//
#include <hip/hip_runtime.h>
#include <math.h>

#define BATCH 4
#define CIN   512
#define PABN  64
#define HW    4096
#define PROW  4356            // 66*66 padded pixel rows

typedef __attribute__((ext_vector_type(8))) short bfrag;   // 8 bf16
typedef __attribute__((ext_vector_type(4))) float ffrag;   // 4 fp32
#define MFMA(a, b, c) __builtin_amdgcn_mfma_f32_16x16x32_bf16(a, b, c, 0, 0, 0)

__device__ __forceinline__ void gload16(const void* g, void* l) {
    __builtin_amdgcn_global_load_lds(
        (const __attribute__((address_space(1))) unsigned int*)g,
        (__attribute__((address_space(3))) unsigned int*)l, 16, 0, 0);
}

__device__ __forceinline__ unsigned f2bf(float f) {   // fp32 -> bf16 bits, RNE
    unsigned u = __float_as_uint(f);
    return (u + 0x7fffu + ((u >> 16) & 1u)) >> 16;
}

// padded row index for pixel n: (h+1)*66 + (w+1) = n + 2*(n>>6) + 67
__device__ __forceinline__ int prow(int n) { return n + 2 * (n >> 6) + 67; }

// ---------------------------------------------------------------------------
__global__ __launch_bounds__(64) void k_zero(float* __restrict__ Z) {
    if (threadIdx.x < 16) Z[threadIdx.x] = 0.f;
}

__global__ __launch_bounds__(256) void k_fill0(uint4* __restrict__ p) {
    uint4 z; z.x = z.y = z.z = z.w = 0u;
    p[(size_t)blockIdx.x * 256 + threadIdx.x] = z;
}

// w_top/w_cen [64][512] fp32 -> bf16 (layout kept: [p][i], K=i contiguous)
__global__ __launch_bounds__(256) void k_wpc(const float* __restrict__ wt,
        const float* __restrict__ wc, short* __restrict__ ot, short* __restrict__ oc) {
    const float* src = blockIdx.y ? wc : wt;
    short* dst       = blockIdx.y ? oc : ot;
    int idx = (blockIdx.x * 256 + threadIdx.x) * 4;
    float4 v = *(const float4*)(src + idx);
    uint2 u;
    u.x = f2bf(v.x) | (f2bf(v.y) << 16);
    u.y = f2bf(v.z) | (f2bf(v.w) << 16);
    *(uint2*)(dst + idx) = u;
}

// w [O][I][3][3] fp32 -> wT[k][o][i] bf16
__global__ __launch_bounds__(256) void k_w9(const float* __restrict__ wb,
        const float* __restrict__ wo, short* __restrict__ wbT, short* __restrict__ woT) {
    const float* w = blockIdx.z ? wo : wb;
    short* wT      = blockIdx.z ? woT : wbT;
    int o = blockIdx.x;
    int i = blockIdx.y * 256 + threadIdx.x;
    const float* src = w + ((size_t)o * CIN + i) * 9;
    float v[9];
#pragma unroll
    for (int k = 0; k < 9; k++) v[k] = src[k];
#pragma unroll
    for (int k = 0; k < 9; k++)
        wT[((size_t)k * CIN + o) * CIN + i] = (short)f2bf(v[k]);
}

// ---------------------------------------------------------------------------
// x [B][512][4096] fp32 (-> optionally + O pixel-major fp32... see ADD) ->
// pixel-major padded bf16 xp [B][4356][512]. Borders pre-zeroed by k_fill0.
// grid (64 pix-tiles, 8 ch-tiles, B)
template <bool ADD>
__global__ __launch_bounds__(256) void k_padT(const float* __restrict__ x,
        const float* __restrict__ Oc, short* __restrict__ xp) {
    __shared__ float Ts[64][68];
    int t = threadIdx.x;
    int n0 = blockIdx.x * 64, c0 = blockIdx.y * 64, b = blockIdx.z;
    const float* xb = x + ((size_t)b * CIN + c0) * HW;
#pragma unroll
    for (int j = 0; j < 4; j++) {
        int slot = j * 256 + t;
        int r = slot >> 4, col = (slot & 15) * 4;
        float4 v = *(const float4*)(xb + (size_t)r * HW + n0 + col);
        *(float4*)&Ts[r][col] = v;
    }
    __syncthreads();
    short* xpb = xp + (size_t)b * PROW * CIN;
    const float* ob = ADD ? (Oc + (size_t)b * HW * CIN) : nullptr;
#pragma unroll
    for (int j = 0; j < 2; j++) {
        int slot = j * 256 + t;
        int pix = slot >> 3, ch = (slot & 7) * 8;
        int rp = prow(n0 + pix);
        float v[8];
#pragma unroll
        for (int k = 0; k < 8; k++) v[k] = Ts[ch + k][pix];
        if (ADD) {   // O is [n][c] fp32 (raw-reshape == same flat order as [c][hw])
            const float* os = ob + (size_t)(n0 + pix) * CIN + c0 + ch;
#pragma unroll
            for (int k = 0; k < 8; k += 4) {
                float4 o4 = *(const float4*)(os + k);
                v[k] += o4.x; v[k+1] += o4.y; v[k+2] += o4.z; v[k+3] += o4.w;
            }
        }
        unsigned pk[4];
#pragma unroll
        for (int k = 0; k < 4; k++)
            pk[k] = f2bf(v[2*k]) | (f2bf(v[2*k+1]) << 16);
        *(uint4*)(xpb + (size_t)rp * CIN + c0 + ch) = *(uint4*)pk;
    }
}

// ---------------------------------------------------------------------------
// 1x1 convs: xt/xc[n][p] = sum_i xp[n][i]*w[p][i] + bias.  M=p(64), N=n(64), K=512
// grid (64 n-tiles, 8: b*2+which).  LDS rows 32 shorts (64B): swizzle (row>>1)&3.
__global__ __launch_bounds__(256) void k_qk(const short* __restrict__ xp,
        const short* __restrict__ wtop, const short* __restrict__ wcen,
        const float* __restrict__ btop, const float* __restrict__ bcen,
        short* __restrict__ xt, short* __restrict__ xc) {
    __shared__ __align__(16) short As[2048];   // w: 64 rows(p) x 32(i)
    __shared__ __align__(16) short Bs[2048];   // x: 64 rows(n) x 32(i)
    int t = threadIdx.x;
    int n0 = blockIdx.x * 64;
    int b = blockIdx.y >> 1, which = blockIdx.y & 1;
    const short* w    = which ? wcen : wtop;
    const float* bias = which ? bcen : btop;
    short* out        = (which ? xc : xt) + (size_t)b * HW * PABN;
    const short* xb   = xp + (size_t)b * PROW * CIN;

    int arow = t >> 2, ach = t & 3;
    int sch = ach ^ ((arow >> 1) & 3);
    int rp = prow(n0 + arow);
    int lane = t & 63, wid = t >> 6, l15 = lane & 15, q = lane >> 4;
    int wm = wid >> 1, wn = wid & 1;
    int cx = (q ^ ((l15 >> 1) & 3)) * 8;
    ffrag acc[2][2] = {};

    for (int i0 = 0; i0 < CIN; i0 += 32) {
        gload16(w  + (size_t)arow * CIN + i0 + sch * 8, As + t * 8);
        gload16(xb + (size_t)rp   * CIN + i0 + sch * 8, Bs + t * 8);
        __syncthreads();
        bfrag a[2], bb[2];
        a[0]  = *(const bfrag*)(As + (wm * 32 + l15) * 32 + cx);
        a[1]  = *(const bfrag*)(As + (wm * 32 + 16 + l15) * 32 + cx);
        bb[0] = *(const bfrag*)(Bs + (wn * 32 + l15) * 32 + cx);
        bb[1] = *(const bfrag*)(Bs + (wn * 32 + 16 + l15) * 32 + cx);
        acc[0][0] = MFMA(a[0], bb[0], acc[0][0]);
        acc[0][1] = MFMA(a[0], bb[1], acc[0][1]);
        acc[1][0] = MFMA(a[1], bb[0], acc[1][0]);
        acc[1][1] = MFMA(a[1], bb[1], acc[1][1]);
        __syncthreads();
    }
#pragma unroll
    for (int mi = 0; mi < 2; mi++) {
        int p = wm * 32 + mi * 16 + q * 4;
        float4 bv = *(const float4*)(bias + p);
#pragma unroll
        for (int ni = 0; ni < 2; ni++) {
            int nn = n0 + wn * 32 + ni * 16 + l15;
            ffrag v = acc[mi][ni];
            uint2 u;
            u.x = f2bf(v.x + bv.x) | (f2bf(v.y + bv.y) << 16);
            u.y = f2bf(v.z + bv.z) | (f2bf(v.w + bv.w) << 16);
            *(uint2*)(out + (size_t)nn * PABN + p) = u;
        }
    }
}

// ---------------------------------------------------------------------------
// conv3x3: out = conv(in, wT) + bias.  M=n(128), N=o(128), K=i over 9 taps.
// BK=64: LDS rows 64 shorts (128B), 8 chunks: swizzle chunk ^ (row&7).
// grid (32 n-tiles, 4 o-tiles, B)
template <bool FP32OUT>
__global__ __launch_bounds__(256) void k_conv(const short* __restrict__ xin,
        const short* __restrict__ wT, const float* __restrict__ bias,
        void* __restrict__ outv) {
    __shared__ __align__(16) short As[8192];   // pixels: 128 x 64
    __shared__ __align__(16) short Bs[8192];   // weights: 128(o) x 64
    int t = threadIdx.x;
    int n0 = blockIdx.x * 128, o0 = blockIdx.y * 128, b = blockIdx.z;
    const short* xb = xin + (size_t)b * PROW * CIN;
    int lane = t & 63, wid = t >> 6, l15 = lane & 15, q = lane >> 4;
    int wm = wid >> 1, wn = wid & 1;
    int arow = t >> 3, ach = t & 7;
    int sch = ach ^ (arow & 7);             // j*32 doesn't change row&7
    int pr[4];
#pragma unroll
    for (int j = 0; j < 4; j++) pr[j] = prow(n0 + j * 32 + arow);
    ffrag acc[4][4] = {};

    for (int k9 = 0; k9 < 9; k9++) {
        int kh = k9 / 3, kw = k9 - kh * 3;
        int sh = (kh - 1) * 66 + (kw - 1);
        const short* wk = wT + (size_t)k9 * CIN * CIN;
        for (int i0 = 0; i0 < CIN; i0 += 64) {
#pragma unroll
            for (int j = 0; j < 4; j++) {
                gload16(xb + (size_t)(pr[j] + sh) * CIN + i0 + sch * 8,
                        As + (j * 256 + t) * 8);
                gload16(wk + (size_t)(o0 + j * 32 + arow) * CIN + i0 + sch * 8,
                        Bs + (j * 256 + t) * 8);
            }
            __syncthreads();
#pragma unroll
            for (int kc = 0; kc < 2; kc++) {
                int cx = (((kc * 4 + q) ^ (l15 & 7))) * 8;
                bfrag a[4], bb[4];
#pragma unroll
                for (int mi = 0; mi < 4; mi++)
                    a[mi] = *(const bfrag*)(As + (wm * 64 + mi * 16 + l15) * 64 + cx);
#pragma unroll
                for (int ni = 0; ni < 4; ni++)
                    bb[ni] = *(const bfrag*)(Bs + (wn * 64 + ni * 16 + l15) * 64 + cx);
#pragma unroll
                for (int mi = 0; mi < 4; mi++)
#pragma unroll
                    for (int ni = 0; ni < 4; ni++)
                        acc[mi][ni] = MFMA(a[mi], bb[ni], acc[mi][ni]);
            }
            __syncthreads();
        }
    }
#pragma unroll
    for (int ni = 0; ni < 4; ni++) {
        int o = o0 + wn * 64 + ni * 16 + l15;
        float bv = bias[o];
#pragma unroll
        for (int mi = 0; mi < 4; mi++) {
            int n = n0 + wm * 64 + mi * 16 + q * 4;
            ffrag v = acc[mi][ni];
            if (FP32OUT) {
                float* out = (float*)outv + (size_t)b * CIN * HW;
                *(float4*)(out + (size_t)o * HW + n) =
                    make_float4(v.x + bv, v.y + bv, v.z + bv, v.w + bv);
            } else {
                short* out = (short*)outv + (size_t)b * CIN * HW;
                uint2 u;
                u.x = f2bf(v.x + bv) | (f2bf(v.y + bv) << 16);
                u.y = f2bf(v.z + bv) | (f2bf(v.w + bv) << 16);
                *(uint2*)(out + (size_t)o * HW + n) = u;
            }
        }
    }
}

// ---------------------------------------------------------------------------
// S-pass: P[n][m] = exp(sum_p xc[n][p]*xt[m][p]); Z[b] += sum P.
// M=n(128), N=m(128), K=64. grid (32 m-tiles, 32 n-tiles, cb batches)
__global__ __launch_bounds__(256) void k_S(const short* __restrict__ xc,
        const short* __restrict__ xt, short* __restrict__ P,
        float* __restrict__ Z, int b0) {
    __shared__ __align__(16) short SM[16384];  // As [128][64] | Bs [128][64]; reused as T
    short* As = SM;
    short* Bs = SM + 8192;
    int t = threadIdx.x;
    int m0 = blockIdx.x * 128, n0 = blockIdx.y * 128;
    int lb = blockIdx.z, b = b0 + lb;
    const short* xcb = xc + (size_t)b * HW * PABN;
    const short* xtb = xt + (size_t)b * HW * PABN;
    short* Pb = P + (size_t)lb * HW * HW;
    int arow = t >> 3, ach = t & 7;
    int sch = ach ^ (arow & 7);
#pragma unroll
    for (int j = 0; j < 4; j++) {
        int row = j * 32 + arow;
        gload16(xcb + (size_t)(n0 + row) * PABN + sch * 8, As + (j * 256 + t) * 8);
        gload16(xtb + (size_t)(m0 + row) * PABN + sch * 8, Bs + (j * 256 + t) * 8);
    }
    __syncthreads();
    int lane = t & 63, wid = t >> 6, l15 = lane & 15, q = lane >> 4;
    int wm = wid >> 1, wn = wid & 1;
    ffrag acc[4][4] = {};
#pragma unroll
    for (int kc = 0; kc < 2; kc++) {
        int cx = (((kc * 4 + q) ^ (l15 & 7))) * 8;
        bfrag a[4], bb[4];
#pragma unroll
        for (int mi = 0; mi < 4; mi++)
            a[mi] = *(const bfrag*)(As + (wm * 64 + mi * 16 + l15) * 64 + cx);
#pragma unroll
        for (int ni = 0; ni < 4; ni++)
            bb[ni] = *(const bfrag*)(Bs + (wn * 64 + ni * 16 + l15) * 64 + cx);
#pragma unroll
        for (int mi = 0; mi < 4; mi++)
#pragma unroll
            for (int ni = 0; ni < 4; ni++)
                acc[mi][ni] = MFMA(a[mi], bb[ni], acc[mi][ni]);
    }
    __syncthreads();                    // tiles dead; reuse SM as transpose buf
    short* T = SM + wid * 4096;         // per-wave 64x64 bf16
    float zacc = 0.f;
#pragma unroll
    for (int mi = 0; mi < 4; mi++)
#pragma unroll
        for (int ni = 0; ni < 4; ni++) {
            ffrag v = acc[mi][ni];
#pragma unroll
            for (int r = 0; r < 4; r++) {
                float e = __expf(v[r]);
                zacc += e;
                T[(mi * 16 + q * 4 + r) * 64 + ni * 16 + l15] = (short)f2bf(e);
            }
        }
    __syncthreads();
#pragma unroll
    for (int p = 0; p < 8; p++) {
        int r64 = p * 8 + (lane >> 3), c64 = (lane & 7) * 8;
        uint4 v = *(const uint4*)(T + r64 * 64 + c64);
        *(uint4*)(Pb + (size_t)(n0 + wm * 64 + r64) * HW + m0 + wn * 64 + c64) = v;
    }
#pragma unroll
    for (int off = 32; off > 0; off >>= 1) zacc += __shfl_down(zacc, off, 64);
    if (lane == 0) atomicAdd(Z + b, zacc);
}

// ---------------------------------------------------------------------------
// PV: O[n][c] = invZ * sum_m xb[c][m]*P[n][m].  M=c(64), N=n(128), K=4096, BK=64.
// grid (32 n-tiles, 8 c-tiles, cb batches)
__global__ __launch_bounds__(256) void k_PV(const short* __restrict__ xb,
        const short* __restrict__ P, const float* __restrict__ Z,
        float* __restrict__ O, int b0) {
    __shared__ __align__(16) short As[4096];   // xb: 64(c) x 64(m)
    __shared__ __align__(16) short Bs[8192];   // P : 128(n) x 64(m)
    int t = threadIdx.x;
    int n0 = blockIdx.x * 128, c0 = blockIdx.y * 64;
    int lb = blockIdx.z, b = b0 + lb;
    const short* xbb = xb + (size_t)b * CIN * HW;
    const short* Pb  = P + (size_t)lb * HW * HW;
    int lane = t & 63, wid = t >> 6, l15 = lane & 15, q = lane >> 4;
    int wm = wid >> 1, wn = wid & 1;
    int arow = t >> 3, ach = t & 7;
    int sch = ach ^ (arow & 7);
    ffrag acc[2][4] = {};
    for (int m0 = 0; m0 < HW; m0 += 64) {
#pragma unroll
        for (int j = 0; j < 2; j++)
            gload16(xbb + (size_t)(c0 + j * 32 + arow) * HW + m0 + sch * 8,
                    As + (j * 256 + t) * 8);
#pragma unroll
        for (int j = 0; j < 4; j++)
            gload16(Pb + (size_t)(n0 + j * 32 + arow) * HW + m0 + sch * 8,
                    Bs + (j * 256 + t) * 8);
        __syncthreads();
#pragma unroll
        for (int kc = 0; kc < 2; kc++) {
            int cx = (((kc * 4 + q) ^ (l15 & 7))) * 8;
            bfrag a[2], bb[4];
#pragma unroll
            for (int mi = 0; mi < 2; mi++)
                a[mi] = *(const bfrag*)(As + (wm * 32 + mi * 16 + l15) * 64 + cx);
#pragma unroll
            for (int ni = 0; ni < 4; ni++)
                bb[ni] = *(const bfrag*)(Bs + (wn * 64 + ni * 16 + l15) * 64 + cx);
#pragma unroll
            for (int mi = 0; mi < 2; mi++)
#pragma unroll
                for (int ni = 0; ni < 4; ni++)
                    acc[mi][ni] = MFMA(a[mi], bb[ni], acc[mi][ni]);
        }
        __syncthreads();
    }
    float invZ = 1.0f / Z[b];
    float* Ob = O + (size_t)b * HW * CIN;
#pragma unroll
    for (int mi = 0; mi < 2; mi++)
#pragma unroll
        for (int ni = 0; ni < 4; ni++) {
            int c = c0 + wm * 32 + mi * 16 + q * 4;
            int n = n0 + wn * 64 + ni * 16 + l15;
            ffrag v = acc[mi][ni];
            *(float4*)(Ob + (size_t)n * CIN + c) =
                make_float4(v.x * invZ, v.y * invZ, v.z * invZ, v.w * invZ);
        }
}

// ---------------------------------------------------------------------------
extern "C" void kernel_launch(void* const* d_in, const int* in_sizes, int n_in,
                              void* d_out, int out_size, void* d_ws, size_t ws_size,
                              hipStream_t stream) {
    const float* x     = (const float*)d_in[0];
    const float* w_top = (const float*)d_in[1];
    const float* b_top = (const float*)d_in[2];
    const float* w_cen = (const float*)d_in[3];
    const float* b_cen = (const float*)d_in[4];
    const float* w_bot = (const float*)d_in[5];
    const float* b_bot = (const float*)d_in[6];
    const float* w_out = (const float*)d_in[7];
    const float* b_out = (const float*)d_in[8];

    char* W = (char*)d_ws;
    short* xp  = (short*)(W);               // 17,842,176 B (also reused as yp)
    short* xt  = (short*)(W + 17842176);    //  2,097,152
    short* xc  = (short*)(W + 19939328);    //  2,097,152
    short* wtb = (short*)(W + 22036480);    //     65,536
    short* wcb = (short*)(W + 22102016);    //     65,536
    short* wbT = (short*)(W + 22167552);    //  4,718,592
    short* woT = (short*)(W + 26886144);    //  4,718,592
    short* xbc = (short*)(W + 31604736);    // 16,777,216
    float* O   = (float*)(W + 48381952);    // 33,554,432
    float* Z   = (float*)(W + 81936384);    //        512
    short* P   = (short*)(W + 81936896);    // 33,554,432 * chunk

    // pick largest batch-chunk for P that fits the workspace (deterministic)
    size_t pB = (size_t)HW * HW * 2;
    size_t base = 81936896;
    int chunk = 1;
    if      (ws_size >= base + 4 * pB) chunk = 4;
    else if (ws_size >= base + 2 * pB) chunk = 2;

    k_zero<<<1, 64, 0, stream>>>(Z);
    k_fill0<<<4356, 256, 0, stream>>>((uint4*)xp);           // zero padded buffer
    k_wpc<<<dim3(32, 2), 256, 0, stream>>>(w_top, w_cen, wtb, wcb);
    k_w9<<<dim3(512, 2, 2), 256, 0, stream>>>(w_bot, w_out, wbT, woT);
    k_padT<false><<<dim3(64, 8, BATCH), 256, 0, stream>>>(x, nullptr, xp);
    k_qk<<<dim3(64, 8), 256, 0, stream>>>(xp, wtb, wcb, b_top, b_cen, xt, xc);
    k_conv<false><<<dim3(32, 4, BATCH), 256, 0, stream>>>(xp, wbT, b_bot, xbc);
    for (int b0 = 0; b0 < BATCH; b0 += chunk) {
        int cb = BATCH - b0 < chunk ? BATCH - b0 : chunk;
        k_S<<<dim3(32, 32, cb), 256, 0, stream>>>(xc, xt, P, Z, b0);
        k_PV<<<dim3(32, 8, cb), 256, 0, stream>>>(xbc, P, Z, O, b0);
    }
    k_padT<true><<<dim3(64, 8, BATCH), 256, 0, stream>>>(x, O, xp);  // y -> xp
    k_conv<true><<<dim3(32, 4, BATCH), 256, 0, stream>>>(xp, woT, b_out, (float*)d_out);
}

// Round 5
// 427.980 us; speedup vs baseline: 8.5744x; 1.3670x over previous
//
#include <hip/hip_runtime.h>
#include <math.h>

#define BATCH 4
#define CIN   512
#define PABN  64
#define HW    4096
#define PROW  4356            // 66*66 padded pixel rows

typedef __attribute__((ext_vector_type(8))) short bfrag;   // 8 bf16
typedef __attribute__((ext_vector_type(4))) float ffrag;   // 4 fp32
#define MFMA(a, b, c) __builtin_amdgcn_mfma_f32_16x16x32_bf16(a, b, c, 0, 0, 0)

__device__ __forceinline__ void gload16(const void* g, void* l) {
    __builtin_amdgcn_global_load_lds(
        (const __attribute__((address_space(1))) unsigned int*)g,
        (__attribute__((address_space(3))) unsigned int*)l, 16, 0, 0);
}

__device__ __forceinline__ unsigned f2bf(float f) {   // fp32 -> bf16 bits, RNE
    unsigned u = __float_as_uint(f);
    return (u + 0x7fffu + ((u >> 16) & 1u)) >> 16;
}

// padded row index for pixel n: (h+1)*66 + (w+1) = n + 2*(n>>6) + 67
__device__ __forceinline__ int prow(int n) { return n + 2 * (n >> 6) + 67; }

// ---------------------------------------------------------------------------
__global__ __launch_bounds__(256) void k_fill0(uint4* __restrict__ p) {
    uint4 z; z.x = z.y = z.z = z.w = 0u;
    p[(size_t)blockIdx.x * 256 + threadIdx.x] = z;
}

// w_top/w_cen [64][512] fp32 -> bf16 (layout kept: [p][i], K=i contiguous)
__global__ __launch_bounds__(256) void k_wpc(const float* __restrict__ wt,
        const float* __restrict__ wc, short* __restrict__ ot, short* __restrict__ oc) {
    const float* src = blockIdx.y ? wc : wt;
    short* dst       = blockIdx.y ? oc : ot;
    int idx = (blockIdx.x * 256 + threadIdx.x) * 4;
    float4 v = *(const float4*)(src + idx);
    uint2 u;
    u.x = f2bf(v.x) | (f2bf(v.y) << 16);
    u.y = f2bf(v.z) | (f2bf(v.w) << 16);
    *(uint2*)(dst + idx) = u;
}

// w [O][I][3][3] fp32 -> wT[k][o][i] bf16
__global__ __launch_bounds__(256) void k_w9(const float* __restrict__ wb,
        const float* __restrict__ wo, short* __restrict__ wbT, short* __restrict__ woT) {
    const float* w = blockIdx.z ? wo : wb;
    short* wT      = blockIdx.z ? woT : wbT;
    int o = blockIdx.x;
    int i = blockIdx.y * 256 + threadIdx.x;
    const float* src = w + ((size_t)o * CIN + i) * 9;
    float v[9];
#pragma unroll
    for (int k = 0; k < 9; k++) v[k] = src[k];
#pragma unroll
    for (int k = 0; k < 9; k++)
        wT[((size_t)k * CIN + o) * CIN + i] = (short)f2bf(v[k]);
}

// ---------------------------------------------------------------------------
// x [B][512][4096] fp32 (ADD: + O [n][c] fp32, raw-reshape-equivalent) ->
// pixel-major padded bf16 xp [B][4356][512]. Borders pre-zeroed by k_fill0.
// grid (64 pix-tiles, 8 ch-tiles, B)
template <bool ADD>
__global__ __launch_bounds__(256) void k_padT(const float* __restrict__ x,
        const float* __restrict__ Oc, short* __restrict__ xp) {
    __shared__ float Ts[64][68];
    int t = threadIdx.x;
    int n0 = blockIdx.x * 64, c0 = blockIdx.y * 64, b = blockIdx.z;
    const float* xb = x + ((size_t)b * CIN + c0) * HW;
#pragma unroll
    for (int j = 0; j < 4; j++) {
        int slot = j * 256 + t;
        int r = slot >> 4, col = (slot & 15) * 4;
        float4 v = *(const float4*)(xb + (size_t)r * HW + n0 + col);
        *(float4*)&Ts[r][col] = v;
    }
    __syncthreads();
    short* xpb = xp + (size_t)b * PROW * CIN;
    const float* ob = ADD ? (Oc + (size_t)b * HW * CIN) : nullptr;
#pragma unroll
    for (int j = 0; j < 2; j++) {
        int slot = j * 256 + t;
        int pix = slot >> 3, ch = (slot & 7) * 8;
        int rp = prow(n0 + pix);
        float v[8];
#pragma unroll
        for (int k = 0; k < 8; k++) v[k] = Ts[ch + k][pix];
        if (ADD) {
            const float* os = ob + (size_t)(n0 + pix) * CIN + c0 + ch;
#pragma unroll
            for (int k = 0; k < 8; k += 4) {
                float4 o4 = *(const float4*)(os + k);
                v[k] += o4.x; v[k+1] += o4.y; v[k+2] += o4.z; v[k+3] += o4.w;
            }
        }
        unsigned pk[4];
#pragma unroll
        for (int k = 0; k < 4; k++)
            pk[k] = f2bf(v[2*k]) | (f2bf(v[2*k+1]) << 16);
        *(uint4*)(xpb + (size_t)rp * CIN + c0 + ch) = *(uint4*)pk;
    }
}

// ---------------------------------------------------------------------------
// 1x1 convs: xt/xc[n][p] = sum_i xp[n][i]*w[p][i] + bias.  M=p(64), N=n(64), K=512
// grid (64 n-tiles, 8: b*2+which)
__global__ __launch_bounds__(256) void k_qk(const short* __restrict__ xp,
        const short* __restrict__ wtop, const short* __restrict__ wcen,
        const float* __restrict__ btop, const float* __restrict__ bcen,
        short* __restrict__ xt, short* __restrict__ xc) {
    __shared__ __align__(16) short As[2048];   // w: 64 rows(p) x 32(i)
    __shared__ __align__(16) short Bs[2048];   // x: 64 rows(n) x 32(i)
    int t = threadIdx.x;
    int n0 = blockIdx.x * 64;
    int b = blockIdx.y >> 1, which = blockIdx.y & 1;
    const short* w    = which ? wcen : wtop;
    const float* bias = which ? bcen : btop;
    short* out        = (which ? xc : xt) + (size_t)b * HW * PABN;
    const short* xb   = xp + (size_t)b * PROW * CIN;

    int arow = t >> 2, ach = t & 3;
    int sch = ach ^ ((arow >> 1) & 3);
    int rp = prow(n0 + arow);
    int lane = t & 63, wid = t >> 6, l15 = lane & 15, q = lane >> 4;
    int wm = wid >> 1, wn = wid & 1;
    int cx = (q ^ ((l15 >> 1) & 3)) * 8;
    ffrag acc[2][2] = {};

    for (int i0 = 0; i0 < CIN; i0 += 32) {
        gload16(w  + (size_t)arow * CIN + i0 + sch * 8, As + t * 8);
        gload16(xb + (size_t)rp   * CIN + i0 + sch * 8, Bs + t * 8);
        __syncthreads();
        bfrag a[2], bb[2];
        a[0]  = *(const bfrag*)(As + (wm * 32 + l15) * 32 + cx);
        a[1]  = *(const bfrag*)(As + (wm * 32 + 16 + l15) * 32 + cx);
        bb[0] = *(const bfrag*)(Bs + (wn * 32 + l15) * 32 + cx);
        bb[1] = *(const bfrag*)(Bs + (wn * 32 + 16 + l15) * 32 + cx);
        acc[0][0] = MFMA(a[0], bb[0], acc[0][0]);
        acc[0][1] = MFMA(a[0], bb[1], acc[0][1]);
        acc[1][0] = MFMA(a[1], bb[0], acc[1][0]);
        acc[1][1] = MFMA(a[1], bb[1], acc[1][1]);
        __syncthreads();
    }
#pragma unroll
    for (int mi = 0; mi < 2; mi++) {
        int p = wm * 32 + mi * 16 + q * 4;
        float4 bv = *(const float4*)(bias + p);
#pragma unroll
        for (int ni = 0; ni < 2; ni++) {
            int nn = n0 + wn * 32 + ni * 16 + l15;
            ffrag v = acc[mi][ni];
            uint2 u;
            u.x = f2bf(v.x + bv.x) | (f2bf(v.y + bv.y) << 16);
            u.y = f2bf(v.z + bv.z) | (f2bf(v.w + bv.w) << 16);
            *(uint2*)(out + (size_t)nn * PABN + p) = u;
        }
    }
}

// ---------------------------------------------------------------------------
// conv3x3: out = conv(in, wT) + bias.  M=n(128), N=o(128), K=i over 9 taps.
// BK=64: LDS rows 64 shorts (128B), 8 chunks: swizzle chunk ^ (row&7).
// grid (32 n-tiles, 4 o-tiles, B)
template <bool FP32OUT>
__global__ __launch_bounds__(256) void k_conv(const short* __restrict__ xin,
        const short* __restrict__ wT, const float* __restrict__ bias,
        void* __restrict__ outv) {
    __shared__ __align__(16) short As[8192];   // pixels: 128 x 64
    __shared__ __align__(16) short Bs[8192];   // weights: 128(o) x 64
    int t = threadIdx.x;
    int n0 = blockIdx.x * 128, o0 = blockIdx.y * 128, b = blockIdx.z;
    const short* xb = xin + (size_t)b * PROW * CIN;
    int lane = t & 63, wid = t >> 6, l15 = lane & 15, q = lane >> 4;
    int wm = wid >> 1, wn = wid & 1;
    int arow = t >> 3, ach = t & 7;
    int sch = ach ^ (arow & 7);
    int pr[4];
#pragma unroll
    for (int j = 0; j < 4; j++) pr[j] = prow(n0 + j * 32 + arow);
    ffrag acc[4][4] = {};

    for (int k9 = 0; k9 < 9; k9++) {
        int kh = k9 / 3, kw = k9 - kh * 3;
        int sh = (kh - 1) * 66 + (kw - 1);
        const short* wk = wT + (size_t)k9 * CIN * CIN;
        for (int i0 = 0; i0 < CIN; i0 += 64) {
#pragma unroll
            for (int j = 0; j < 4; j++) {
                gload16(xb + (size_t)(pr[j] + sh) * CIN + i0 + sch * 8,
                        As + (j * 256 + t) * 8);
                gload16(wk + (size_t)(o0 + j * 32 + arow) * CIN + i0 + sch * 8,
                        Bs + (j * 256 + t) * 8);
            }
            __syncthreads();
#pragma unroll
            for (int kc = 0; kc < 2; kc++) {
                int cx = (((kc * 4 + q) ^ (l15 & 7))) * 8;
                bfrag a[4], bb[4];
#pragma unroll
                for (int mi = 0; mi < 4; mi++)
                    a[mi] = *(const bfrag*)(As + (wm * 64 + mi * 16 + l15) * 64 + cx);
#pragma unroll
                for (int ni = 0; ni < 4; ni++)
                    bb[ni] = *(const bfrag*)(Bs + (wn * 64 + ni * 16 + l15) * 64 + cx);
#pragma unroll
                for (int mi = 0; mi < 4; mi++)
#pragma unroll
                    for (int ni = 0; ni < 4; ni++)
                        acc[mi][ni] = MFMA(a[mi], bb[ni], acc[mi][ni]);
            }
            __syncthreads();
        }
    }
#pragma unroll
    for (int ni = 0; ni < 4; ni++) {
        int o = o0 + wn * 64 + ni * 16 + l15;
        float bv = bias[o];
#pragma unroll
        for (int mi = 0; mi < 4; mi++) {
            int n = n0 + wm * 64 + mi * 16 + q * 4;
            ffrag v = acc[mi][ni];
            if (FP32OUT) {
                float* out = (float*)outv + (size_t)b * CIN * HW;
                *(float4*)(out + (size_t)o * HW + n) =
                    make_float4(v.x + bv, v.y + bv, v.z + bv, v.w + bv);
            } else {
                short* out = (short*)outv + (size_t)b * CIN * HW;
                uint2 u;
                u.x = f2bf(v.x + bv) | (f2bf(v.y + bv) << 16);
                u.y = f2bf(v.z + bv) | (f2bf(v.w + bv) << 16);
                *(uint2*)(out + (size_t)o * HW + n) = u;
            }
        }
    }
}

// ---------------------------------------------------------------------------
// S-pass: P[n][m] = exp(sum_p xc[n][p]*xt[m][p]); Zbuf[b][block] = sum P_tile.
// M=n(128), N=m(128), K=64. grid (32 m-tiles, 32 n-tiles, cb batches)
// T transpose buffer: row stride 72 shorts (144B) -> conflict-free-ish.
__global__ __launch_bounds__(256) void k_S(const short* __restrict__ xc,
        const short* __restrict__ xt, short* __restrict__ P,
        float* __restrict__ Zbuf, int b0) {
    __shared__ __align__(16) short SM[18432]; // As[8192]|Bs[8192]; reused as T (4x4608)
    __shared__ float red[4];
    short* As = SM;
    short* Bs = SM + 8192;
    int t = threadIdx.x;
    int m0 = blockIdx.x * 128, n0 = blockIdx.y * 128;
    int lb = blockIdx.z, b = b0 + lb;
    const short* xcb = xc + (size_t)b * HW * PABN;
    const short* xtb = xt + (size_t)b * HW * PABN;
    short* Pb = P + (size_t)lb * HW * HW;
    int arow = t >> 3, ach = t & 7;
    int sch = ach ^ (arow & 7);
#pragma unroll
    for (int j = 0; j < 4; j++) {
        int row = j * 32 + arow;
        gload16(xcb + (size_t)(n0 + row) * PABN + sch * 8, As + (j * 256 + t) * 8);
        gload16(xtb + (size_t)(m0 + row) * PABN + sch * 8, Bs + (j * 256 + t) * 8);
    }
    __syncthreads();
    int lane = t & 63, wid = t >> 6, l15 = lane & 15, q = lane >> 4;
    int wm = wid >> 1, wn = wid & 1;
    ffrag acc[4][4] = {};
#pragma unroll
    for (int kc = 0; kc < 2; kc++) {
        int cx = (((kc * 4 + q) ^ (l15 & 7))) * 8;
        bfrag a[4], bb[4];
#pragma unroll
        for (int mi = 0; mi < 4; mi++)
            a[mi] = *(const bfrag*)(As + (wm * 64 + mi * 16 + l15) * 64 + cx);
#pragma unroll
        for (int ni = 0; ni < 4; ni++)
            bb[ni] = *(const bfrag*)(Bs + (wn * 64 + ni * 16 + l15) * 64 + cx);
#pragma unroll
        for (int mi = 0; mi < 4; mi++)
#pragma unroll
            for (int ni = 0; ni < 4; ni++)
                acc[mi][ni] = MFMA(a[mi], bb[ni], acc[mi][ni]);
    }
    __syncthreads();                    // tiles dead; reuse SM as transpose buf
    short* T = SM + wid * 4608;         // per-wave 64 x 72 bf16
    float zacc = 0.f;
#pragma unroll
    for (int mi = 0; mi < 4; mi++)
#pragma unroll
        for (int ni = 0; ni < 4; ni++) {
            ffrag v = acc[mi][ni];
#pragma unroll
            for (int r = 0; r < 4; r++) {
                float e = __expf(v[r]);
                zacc += e;
                T[(mi * 16 + q * 4 + r) * 72 + ni * 16 + l15] = (short)f2bf(e);
            }
        }
    __syncthreads();
#pragma unroll
    for (int p = 0; p < 8; p++) {
        int r64 = p * 8 + (lane >> 3), c64 = (lane & 7) * 8;
        uint4 v = *(const uint4*)(T + r64 * 72 + c64);
        *(uint4*)(Pb + (size_t)(n0 + wm * 64 + r64) * HW + m0 + wn * 64 + c64) = v;
    }
#pragma unroll
    for (int off = 32; off > 0; off >>= 1) zacc += __shfl_down(zacc, off, 64);
    if (lane == 0) red[wid] = zacc;
    __syncthreads();
    if (t == 0)
        Zbuf[b * 1024 + blockIdx.y * 32 + blockIdx.x] =
            red[0] + red[1] + red[2] + red[3];
}

// ---------------------------------------------------------------------------
// Reduce Zbuf[b][0..1023] -> Z[b] for batches [b0, b0+cb). 1 block, 256 thr.
__global__ __launch_bounds__(256) void k_red(const float* __restrict__ Zbuf,
        float* __restrict__ Z, int b0, int cb) {
    int wid = threadIdx.x >> 6, lane = threadIdx.x & 63;
    if (wid >= cb) return;
    int b = b0 + wid;
    float s = 0.f;
#pragma unroll
    for (int j = 0; j < 16; j++) s += Zbuf[b * 1024 + j * 64 + lane];
#pragma unroll
    for (int off = 32; off > 0; off >>= 1) s += __shfl_down(s, off, 64);
    if (lane == 0) Z[b] = s;
}

// ---------------------------------------------------------------------------
// PV: O[n][c] = invZ * sum_m xb[c][m]*P[n][m].  M=c(64), N=n(128), K=4096, BK=64.
// grid (32 n-tiles, 8 c-tiles, cb batches)
__global__ __launch_bounds__(256) void k_PV(const short* __restrict__ xb,
        const short* __restrict__ P, const float* __restrict__ Z,
        float* __restrict__ O, int b0) {
    __shared__ __align__(16) short As[4096];   // xb: 64(c) x 64(m)
    __shared__ __align__(16) short Bs[8192];   // P : 128(n) x 64(m)
    int t = threadIdx.x;
    int n0 = blockIdx.x * 128, c0 = blockIdx.y * 64;
    int lb = blockIdx.z, b = b0 + lb;
    const short* xbb = xb + (size_t)b * CIN * HW;
    const short* Pb  = P + (size_t)lb * HW * HW;
    int lane = t & 63, wid = t >> 6, l15 = lane & 15, q = lane >> 4;
    int wm = wid >> 1, wn = wid & 1;
    int arow = t >> 3, ach = t & 7;
    int sch = ach ^ (arow & 7);
    ffrag acc[2][4] = {};
    for (int m0 = 0; m0 < HW; m0 += 64) {
#pragma unroll
        for (int j = 0; j < 2; j++)
            gload16(xbb + (size_t)(c0 + j * 32 + arow) * HW + m0 + sch * 8,
                    As + (j * 256 + t) * 8);
#pragma unroll
        for (int j = 0; j < 4; j++)
            gload16(Pb + (size_t)(n0 + j * 32 + arow) * HW + m0 + sch * 8,
                    Bs + (j * 256 + t) * 8);
        __syncthreads();
#pragma unroll
        for (int kc = 0; kc < 2; kc++) {
            int cx = (((kc * 4 + q) ^ (l15 & 7))) * 8;
            bfrag a[2], bb[4];
#pragma unroll
            for (int mi = 0; mi < 2; mi++)
                a[mi] = *(const bfrag*)(As + (wm * 32 + mi * 16 + l15) * 64 + cx);
#pragma unroll
            for (int ni = 0; ni < 4; ni++)
                bb[ni] = *(const bfrag*)(Bs + (wn * 64 + ni * 16 + l15) * 64 + cx);
#pragma unroll
            for (int mi = 0; mi < 2; mi++)
#pragma unroll
                for (int ni = 0; ni < 4; ni++)
                    acc[mi][ni] = MFMA(a[mi], bb[ni], acc[mi][ni]);
        }
        __syncthreads();
    }
    float invZ = 1.0f / Z[b];
    float* Ob = O + (size_t)b * HW * CIN;
#pragma unroll
    for (int mi = 0; mi < 2; mi++)
#pragma unroll
        for (int ni = 0; ni < 4; ni++) {
            int c = c0 + wm * 32 + mi * 16 + q * 4;
            int n = n0 + wn * 64 + ni * 16 + l15;
            ffrag v = acc[mi][ni];
            *(float4*)(Ob + (size_t)n * CIN + c) =
                make_float4(v.x * invZ, v.y * invZ, v.z * invZ, v.w * invZ);
        }
}

// ---------------------------------------------------------------------------
extern "C" void kernel_launch(void* const* d_in, const int* in_sizes, int n_in,
                              void* d_out, int out_size, void* d_ws, size_t ws_size,
                              hipStream_t stream) {
    const float* x     = (const float*)d_in[0];
    const float* w_top = (const float*)d_in[1];
    const float* b_top = (const float*)d_in[2];
    const float* w_cen = (const float*)d_in[3];
    const float* b_cen = (const float*)d_in[4];
    const float* w_bot = (const float*)d_in[5];
    const float* b_bot = (const float*)d_in[6];
    const float* w_out = (const float*)d_in[7];
    const float* b_out = (const float*)d_in[8];

    char* W = (char*)d_ws;
    short* xp   = (short*)(W);               // 17,842,176 B (also reused as yp)
    short* xt   = (short*)(W + 17842176);    //  2,097,152
    short* xc   = (short*)(W + 19939328);    //  2,097,152
    short* wtb  = (short*)(W + 22036480);    //     65,536
    short* wcb  = (short*)(W + 22102016);    //     65,536
    short* wbT  = (short*)(W + 22167552);    //  4,718,592
    short* woT  = (short*)(W + 26886144);    //  4,718,592
    short* xbc  = (short*)(W + 31604736);    // 16,777,216
    float* O    = (float*)(W + 48381952);    // 33,554,432
    float* Z    = (float*)(W + 81936384);    //        512
    float* Zbuf = (float*)(W + 81936896);    //     16,384
    short* P    = (short*)(W + 81953280);    // 33,554,432 * chunk

    // pick largest batch-chunk for P that fits the workspace (deterministic)
    size_t pB = (size_t)HW * HW * 2;
    size_t base = 81953280;
    int chunk = 1;
    if      (ws_size >= base + 4 * pB) chunk = 4;
    else if (ws_size >= base + 2 * pB) chunk = 2;

    k_fill0<<<4356, 256, 0, stream>>>((uint4*)xp);           // zero padded buffer
    k_wpc<<<dim3(32, 2), 256, 0, stream>>>(w_top, w_cen, wtb, wcb);
    k_w9<<<dim3(512, 2, 2), 256, 0, stream>>>(w_bot, w_out, wbT, woT);
    k_padT<false><<<dim3(64, 8, BATCH), 256, 0, stream>>>(x, nullptr, xp);
    k_qk<<<dim3(64, 8), 256, 0, stream>>>(xp, wtb, wcb, b_top, b_cen, xt, xc);
    k_conv<false><<<dim3(32, 4, BATCH), 256, 0, stream>>>(xp, wbT, b_bot, xbc);
    for (int b0 = 0; b0 < BATCH; b0 += chunk) {
        int cb = BATCH - b0 < chunk ? BATCH - b0 : chunk;
        k_S<<<dim3(32, 32, cb), 256, 0, stream>>>(xc, xt, P, Zbuf, b0);
        k_red<<<1, 256, 0, stream>>>(Zbuf, Z, b0, cb);
        k_PV<<<dim3(32, 8, cb), 256, 0, stream>>>(xbc, P, Z, O, b0);
    }
    k_padT<true><<<dim3(64, 8, BATCH), 256, 0, stream>>>(x, O, xp);  // y -> xp
    k_conv<true><<<dim3(32, 4, BATCH), 256, 0, stream>>>(xp, woT, b_out, (float*)d_out);
}